// Round 4
// baseline (313.982 us; speedup 1.0000x reference)
//
#include <hip/hip_runtime.h>
#include <math.h>

#define GELU(v) (0.5f * (v) * (1.0f + erff((v)*0.70710678118654752440f)))

// ---------------- Setup: fold/transpose weights --------------------------------
// fwe2[grp(4)][ic(16)][k(9)][o(8)]            : enc2 transposed    (4608)
// fwd1[grp(2)][ic(32)][phase(4)][tap(4)][o(8)]: dec1 up2-folded    (8192)
// fwd2[ic(16)][phase(4)][tap(4)]              : dec2 up2-folded    (256)
__global__ __launch_bounds__(256) void k_fold(const float* __restrict__ e2w,
                                              const float* __restrict__ d1w,
                                              const float* __restrict__ d2w,
                                              float* __restrict__ fwe2,
                                              float* __restrict__ fwd1,
                                              float* __restrict__ fwd2) {
  int i = blockIdx.x * 256 + threadIdx.x;
  if (i < 4608) {
    int o = i & 7, k = (i >> 3) % 9, ic = (i / 72) & 15, grp = i / 1152;
    fwe2[i] = e2w[((grp * 8 + o) * 16 + ic) * 9 + k];
  } else if (i < 12800) {
    int j = i - 4608;
    int o = j & 7, pt = (j >> 3) & 15, ic = (j >> 7) & 31, grp = j >> 12;
    int a = pt >> 3, b2 = (pt >> 2) & 1, dy = (pt >> 1) & 1, dx = pt & 1;
    const float* wsrc = d1w + ((grp * 8 + o) * 32 + ic) * 9;
    float s = 0.f;
    for (int ky = 0; ky < 3; ++ky) {
      int rm = (a == 0) ? (ky == 0 ? 0 : 1) : (ky == 2 ? 1 : 0);
      if (rm != dy) continue;
      for (int kx = 0; kx < 3; ++kx) {
        int cm = (b2 == 0) ? (kx == 0 ? 0 : 1) : (kx == 2 ? 1 : 0);
        if (cm == dx) s += wsrc[ky * 3 + kx];
      }
    }
    fwd1[j] = s;
  } else if (i < 13056) {
    int j = i - 12800;
    int pt = j & 15, ic = j >> 4;
    int a = pt >> 3, b2 = (pt >> 2) & 1, dy = (pt >> 1) & 1, dx = pt & 1;
    const float* wsrc = d2w + ic * 9;
    float s = 0.f;
    for (int ky = 0; ky < 3; ++ky) {
      int rm = (a == 0) ? (ky == 0 ? 0 : 1) : (ky == 2 ? 1 : 0);
      if (rm != dy) continue;
      for (int kx = 0; kx < 3; ++kx) {
        int cm = (b2 == 0) ? (kx == 0 ? 0 : 1) : (kx == 2 ? 1 : 0);
        if (cm == dx) s += wsrc[ky * 3 + kx];
      }
    }
    fwd2[j] = s;
  }
}

// ---------------- Kernel A: conv1 (1->16) + maxpool2 + gelu --------------------
__global__ __launch_bounds__(256) void k_enc1(const float* __restrict__ x,
                                              const float* __restrict__ w,
                                              const float* __restrict__ bias,
                                              float* __restrict__ h1) {
  int gid = blockIdx.x * 256 + threadIdx.x;
  int xx = gid & 127, yy = (gid >> 7) & 127, b = gid >> 14;
  const float* xp = x + (size_t)b * 65536;
  int r0 = 2 * yy - 1, c0 = 2 * xx - 1;
  float in[4][4];
#pragma unroll
  for (int i = 0; i < 4; ++i) {
    int r = r0 + i;
    bool rv = (unsigned)r < 256u;
#pragma unroll
    for (int j = 0; j < 4; ++j) {
      int c = c0 + j;
      in[i][j] = (rv && (unsigned)c < 256u) ? xp[r * 256 + c] : 0.0f;
    }
  }
  float* op = h1 + (size_t)b * 262144 + yy * 128 + xx;
#pragma unroll
  for (int oc = 0; oc < 16; ++oc) {
    const float* wp = w + oc * 9;  // uniform -> s_load
    float s00 = 0.f, s01 = 0.f, s10 = 0.f, s11 = 0.f;
#pragma unroll
    for (int ky = 0; ky < 3; ++ky)
#pragma unroll
      for (int kx = 0; kx < 3; ++kx) {
        float wv = wp[ky * 3 + kx];
        s00 = fmaf(in[ky][kx], wv, s00);
        s01 = fmaf(in[ky][kx + 1], wv, s01);
        s10 = fmaf(in[ky + 1][kx], wv, s10);
        s11 = fmaf(in[ky + 1][kx + 1], wv, s11);
      }
    float m = fmaxf(fmaxf(s00, s01), fmaxf(s10, s11)) + bias[oc];
    op[oc * 16384] = GELU(m);
  }
}

// ---------------- Kernel B: conv2 (16->32) + maxpool2 --------------------------
// Ping-pong iv tile across ic: issue ic+1's ds_reads before ic's 72-FMA block.
__device__ __forceinline__ void e2_loadiv(float (&dst)[4][4], const float* t) {
#pragma unroll
  for (int dy = 0; dy < 4; ++dy)
#pragma unroll
    for (int dx = 0; dx < 4; ++dx)
      dst[dy][dx] = t[dy * 20 + (dx & 1) * 10 + (dx >> 1)];
}
__device__ __forceinline__ void e2_fma(float (&acc)[4][8], const float (&iv)[4][4],
                                       const float* wp) {
#pragma unroll
  for (int k = 0; k < 9; ++k) {
    int ky = k / 3, kx = k % 3;
#pragma unroll
    for (int o = 0; o < 8; ++o) {
      float wv = wp[k * 8 + o];
      acc[0][o] = fmaf(iv[ky][kx], wv, acc[0][o]);
      acc[1][o] = fmaf(iv[ky][kx + 1], wv, acc[1][o]);
      acc[2][o] = fmaf(iv[ky + 1][kx], wv, acc[2][o]);
      acc[3][o] = fmaf(iv[ky + 1][kx + 1], wv, acc[3][o]);
    }
  }
}
__global__ __launch_bounds__(256) void k_enc2(const float* __restrict__ h1,
                                              const float* __restrict__ fwe2,
                                              const float* __restrict__ bias,
                                              float* __restrict__ h2) {
  __shared__ float st[16 * 360];  // [ic][18 rows][20: evens 0-9, odds 10-19]
  int tid = threadIdx.x;
  int b = blockIdx.y;
  int Y0 = (blockIdx.x >> 3) * 8, X0 = (blockIdx.x & 7) * 8;
  int r_s = 2 * Y0 - 1, c_s = 2 * X0 - 1;
  const float* ip = h1 + (size_t)b * 262144;
  for (int i = tid; i < 5184; i += 256) {  // 16 ic x 18 x 18
    int ic = i / 324, rr = (i % 324) / 18, cc = i % 18;
    int r = r_s + rr, c = c_s + cc;
    float v = ((unsigned)r < 128u && (unsigned)c < 128u) ? ip[ic * 16384 + r * 128 + c] : 0.f;
    st[ic * 360 + rr * 20 + (cc & 1) * 10 + (cc >> 1)] = v;
  }
  __syncthreads();
  int lane = tid & 63;
  int grp = __builtin_amdgcn_readfirstlane(tid >> 6);
  int oc0 = grp * 8;
  int ty = lane >> 3, tx = lane & 7;
  float acc[4][8];
#pragma unroll
  for (int p = 0; p < 4; ++p)
#pragma unroll
    for (int o = 0; o < 8; ++o) acc[p][o] = 0.f;
  const float* wgrp = fwe2 + grp * 1152;  // scalar base
  const float* tb = st + (2 * ty) * 20 + tx;
  float ivA[4][4], ivB[4][4];
  e2_loadiv(ivA, tb);
#pragma unroll 1
  for (int ic = 0; ic < 16; ic += 2) {
    e2_loadiv(ivB, tb + (ic + 1) * 360);
    e2_fma(acc, ivA, wgrp + ic * 72);
    e2_loadiv(ivA, tb + ((ic + 2) & 15) * 360);  // wrap: harmless re-read
    e2_fma(acc, ivB, wgrp + (ic + 1) * 72);
  }
  float* op = h2 + (size_t)b * 131072 + (Y0 + ty) * 64 + X0 + tx;
#pragma unroll
  for (int o = 0; o < 8; ++o) {
    float m = fmaxf(fmaxf(acc[0][o], acc[1][o]), fmaxf(acc[2][o], acc[3][o])) + bias[oc0 + o];
    op[(oc0 + o) * 4096] = m;
  }
}

// ---------------- Kernel C: fused VQ as a GEMM tile [64 tok x 512 codes, K=32] --
// Block = 64 tokens, all 512 codes; 2048 blocks. LDS: f [k][68] (tokens k-major),
// codebook [k][516] (codes k-major, 16B-aligned rows), csq[512]. Per thread:
// 4 tokens x 4 codes register tile per group; per k-step 2 ds_read_b128 feed
// 16 FMAs (LDS demand 0.25 b128/cyc/CU << pipe capacity). Lane map: tq=l>>4
// (token quad, 16-lane broadcast on f), cs=l&15 (code slice, 4-lane broadcast,
// exact 2-way banks on c). 8 groups of 4 codes (stride 64) cover 512 codes.
// Argmin over cs via 4-step shfl_xor butterfly (lexicographic: first-index-wins).
// Epilogue fuses quantize + idxout + commit loss (was k_vq_merge).
__global__ __launch_bounds__(256) void k_vq(float* __restrict__ h2,
                                            const float* __restrict__ cb,
                                            float* __restrict__ idxout,
                                            float* __restrict__ partial) {
  __shared__ __align__(16) float sC[32 * 516];  // codebook [k][516]
  __shared__ __align__(16) float sF[32 * 68];   // tokens   [k][68]
  __shared__ __align__(16) float sQ[512];       // ||c||^2
  __shared__ int sBi[64];
  __shared__ float sred[4];
  int tid = threadIdx.x;
  int blk = blockIdx.x;
  int t0 = blk * 64;
  size_t abase = (size_t)(t0 >> 12) * 131072 + (t0 & 4095);

  // ---- stage f: 64 tokens x 32 ch (coalesced 256B per wave) ----
  {
    int tok = tid & 63, chb = tid >> 6;
#pragma unroll
    for (int r = 0; r < 8; ++r) {
      int ch = chb * 8 + r;
      sF[ch * 68 + tok] = h2[abase + tok + (size_t)ch * 4096];
    }
  }
  // ---- stage codebook transposed: [k][516] ----
  for (int i = tid; i < 16384; i += 256) sC[(i & 31) * 516 + (i >> 5)] = cb[i];
  // ---- stage csq ----
  for (int c2 = tid; c2 < 512; c2 += 256) {
    const float4* row = (const float4*)(cb + (size_t)c2 * 32);
    float s = 0.f;
#pragma unroll
    for (int q = 0; q < 8; ++q) {
      float4 v = row[q];
      s = fmaf(v.x, v.x, s); s = fmaf(v.y, v.y, s);
      s = fmaf(v.z, v.z, s); s = fmaf(v.w, v.w, s);
    }
    sQ[c2] = s;
  }
  __syncthreads();

  int lane = tid & 63, w = tid >> 6;
  int tq = lane >> 4, cs = lane & 15;
  int fbase = w * 16 + tq * 4;  // block-local token quad
  float bd[4];
  int bi4[4];
#pragma unroll
  for (int i = 0; i < 4; ++i) { bd[i] = 3.4e38f; bi4[i] = 0; }

#pragma unroll 1
  for (int j = 0; j < 8; ++j) {
    int cbase = 4 * cs + 64 * j;
    float a0x = 0, a0y = 0, a0z = 0, a0w = 0;
    float a1x = 0, a1y = 0, a1z = 0, a1w = 0;
    float a2x = 0, a2y = 0, a2z = 0, a2w = 0;
    float a3x = 0, a3y = 0, a3z = 0, a3w = 0;
#pragma unroll 8
    for (int k = 0; k < 32; ++k) {
      float4 fv = *(const float4*)(sF + k * 68 + fbase);
      float4 cv = *(const float4*)(sC + k * 516 + cbase);
      a0x = fmaf(fv.x, cv.x, a0x); a0y = fmaf(fv.x, cv.y, a0y);
      a0z = fmaf(fv.x, cv.z, a0z); a0w = fmaf(fv.x, cv.w, a0w);
      a1x = fmaf(fv.y, cv.x, a1x); a1y = fmaf(fv.y, cv.y, a1y);
      a1z = fmaf(fv.y, cv.z, a1z); a1w = fmaf(fv.y, cv.w, a1w);
      a2x = fmaf(fv.z, cv.x, a2x); a2y = fmaf(fv.z, cv.y, a2y);
      a2z = fmaf(fv.z, cv.z, a2z); a2w = fmaf(fv.z, cv.w, a2w);
      a3x = fmaf(fv.w, cv.x, a3x); a3y = fmaf(fv.w, cv.y, a3y);
      a3z = fmaf(fv.w, cv.z, a3z); a3w = fmaf(fv.w, cv.w, a3w);
    }
    float4 cq = *(const float4*)(sQ + cbase);
#define VQ_UPD(I, AX, AY, AZ, AW)                                        \
    {                                                                    \
      float d0 = cq.x - 2.f * AX; float d1 = cq.y - 2.f * AY;            \
      float d2 = cq.z - 2.f * AZ; float d3 = cq.w - 2.f * AW;            \
      if (d0 < bd[I]) { bd[I] = d0; bi4[I] = cbase + 0; }                \
      if (d1 < bd[I]) { bd[I] = d1; bi4[I] = cbase + 1; }                \
      if (d2 < bd[I]) { bd[I] = d2; bi4[I] = cbase + 2; }                \
      if (d3 < bd[I]) { bd[I] = d3; bi4[I] = cbase + 3; }                \
    }
    VQ_UPD(0, a0x, a0y, a0z, a0w)
    VQ_UPD(1, a1x, a1y, a1z, a1w)
    VQ_UPD(2, a2x, a2y, a2z, a2w)
    VQ_UPD(3, a3x, a3y, a3z, a3w)
#undef VQ_UPD
  }

  // ---- reduce over 16 code-slices (lanes stride 1 in low 4 bits) ----
#pragma unroll
  for (int i = 0; i < 4; ++i) {
#pragma unroll
    for (int m = 1; m < 16; m <<= 1) {
      float od = __shfl_xor(bd[i], m, 64);
      int ob = __shfl_xor(bi4[i], m, 64);
      if (od < bd[i] || (od == bd[i] && ob < bi4[i])) { bd[i] = od; bi4[i] = ob; }
    }
  }
  if (cs == 0) {
#pragma unroll
    for (int i = 0; i < 4; ++i) sBi[fbase + i] = bi4[i];
  }
  __syncthreads();

  // ---- epilogue: quantize h2 in place, idxout, commit loss ----
  int tok = tid >> 2, qd = tid & 3;  // token block-local, channel quarter
  int bi = sBi[tok];
  float loss = 0.f;
#pragma unroll
  for (int r = 0; r < 8; ++r) {
    int ch = qd * 8 + r;
    float qv = sC[ch * 516 + bi];
    float fv = sF[ch * 68 + tok];
    float dd = qv - fv;
    loss = fmaf(dd, dd, loss);
    h2[abase + tok + (size_t)ch * 4096] = qv;
  }
  if (qd == 0) idxout[t0 + tok] = (float)bi;
#pragma unroll
  for (int off = 32; off > 0; off >>= 1) loss += __shfl_down(loss, off, 64);
  if (lane == 0) sred[w] = loss;
  __syncthreads();
  if (tid == 0) partial[blk] = (sred[0] + sred[1]) + (sred[2] + sred[3]);
}

// ---------------- Kernel F: finalize commit loss (2048 partials) ---------------
__global__ __launch_bounds__(256) void k_loss(const float* __restrict__ partial,
                                              float* __restrict__ lossout) {
  __shared__ float sred[4];
  int tid = threadIdx.x;
  float v = 0.f;
#pragma unroll
  for (int k = 0; k < 8; ++k) v += partial[tid + 256 * k];
#pragma unroll
  for (int off = 32; off > 0; off >>= 1) v += __shfl_down(v, off, 64);
  if ((tid & 63) == 0) sred[tid >> 6] = v;
  __syncthreads();
  if (tid == 0)
    lossout[0] = ((sred[0] + sred[1]) + (sred[2] + sred[3])) * (1.0f / 4194304.0f);
}

// ---------------- Kernel D: up2 + conv (32->16) + gelu, phase-folded -----------
__device__ __forceinline__ void d1_loadi3(float (&dst)[3][3], const float* t) {
#pragma unroll
  for (int dy = 0; dy < 3; ++dy)
#pragma unroll
    for (int dx = 0; dx < 3; ++dx) dst[dy][dx] = t[dy * 20 + dx];
}
__device__ __forceinline__ void d1_fma(float (&acc)[4][8], const float (&i3)[3][3],
                                       const float* wp) {
#pragma unroll
  for (int p = 0; p < 4; ++p) {
    int a = p >> 1, b2 = p & 1;
#pragma unroll
    for (int tp = 0; tp < 4; ++tp) {
      int dy = tp >> 1, dx = tp & 1;
      float iv = i3[a + dy][b2 + dx];
#pragma unroll
      for (int o2 = 0; o2 < 8; ++o2)
        acc[p][o2] = fmaf(iv, wp[(p * 4 + tp) * 8 + o2], acc[p][o2]);
    }
  }
}
__global__ __launch_bounds__(256) void k_dec1(const float* __restrict__ q,
                                              const float* __restrict__ fwd1,
                                              const float* __restrict__ bias,
                                              float* __restrict__ o) {
  __shared__ float st[32 * 200];  // [ic][10 rows][20]
  int tid = threadIdx.x;
  int b = blockIdx.y;
  int R0 = (blockIdx.x >> 2) * 8, C0 = (blockIdx.x & 3) * 16;
  const float* ip = q + (size_t)b * 131072;
  for (int i = tid; i < 5760; i += 256) {  // 32 ic x 10 x 18
    int ic = i / 180, rr = (i % 180) / 18, cc = i % 18;
    int r = R0 - 1 + rr, c = C0 - 1 + cc;
    st[ic * 200 + rr * 20 + cc] =
        ((unsigned)r < 64u && (unsigned)c < 64u) ? ip[ic * 4096 + r * 64 + c] : 0.f;
  }
  __syncthreads();
  int lane = tid & 63, wid = tid >> 6;
  int qx = wid & 1;
  int grp = __builtin_amdgcn_readfirstlane(wid >> 1);
  int ty = lane >> 3, tx = qx * 8 + (lane & 7);
  float acc[4][8];
#pragma unroll
  for (int p = 0; p < 4; ++p)
#pragma unroll
    for (int o2 = 0; o2 < 8; ++o2) acc[p][o2] = 0.f;
  const float* wb = fwd1 + grp * 4096;
  const float* tb = st + ty * 20 + tx;
  float i3A[3][3], i3B[3][3];
  d1_loadi3(i3A, tb);
#pragma unroll 1
  for (int ic = 0; ic < 32; ic += 2) {
    d1_loadi3(i3B, tb + (ic + 1) * 200);
    d1_fma(acc, i3A, wb + ic * 128);
    d1_loadi3(i3A, tb + ((ic + 2) & 31) * 200);  // wrap: harmless re-read
    d1_fma(acc, i3B, wb + (ic + 1) * 128);
  }
  int Y = 2 * (R0 + ty), X = 2 * (C0 + tx);
#pragma unroll
  for (int o2 = 0; o2 < 8; ++o2) {
    int oc = grp * 8 + o2;
    float bb = bias[oc];
    float* p = o + (size_t)b * 262144 + (size_t)oc * 16384 + Y * 128 + X;
    float2 r0v, r1v;
    r0v.x = GELU(acc[0][o2] + bb);
    r0v.y = GELU(acc[1][o2] + bb);
    r1v.x = GELU(acc[2][o2] + bb);
    r1v.y = GELU(acc[3][o2] + bb);
    *(float2*)p = r0v;
    *(float2*)(p + 128) = r1v;
  }
}

// ---------------- Kernel E: up2 + conv (16->1) + clip, phase-folded ------------
__global__ __launch_bounds__(256) void k_dec2(const float* __restrict__ d1,
                                              const float* __restrict__ fwd2,
                                              const float* __restrict__ bias,
                                              float* __restrict__ out) {
  __shared__ float st[16 * 360];  // [ic][18 rows][20]
  int tid = threadIdx.x;
  int b = blockIdx.y;
  int R0 = (blockIdx.x >> 3) * 16, C0 = (blockIdx.x & 7) * 16;
  const float* ip = d1 + (size_t)b * 262144;
  for (int i = tid; i < 5184; i += 256) {  // 16 ic x 18 x 18
    int ic = i / 324, rr = (i % 324) / 18, cc = i % 18;
    int r = R0 - 1 + rr, c = C0 - 1 + cc;
    st[ic * 360 + rr * 20 + cc] =
        ((unsigned)r < 128u && (unsigned)c < 128u) ? ip[ic * 16384 + r * 128 + c] : 0.f;
  }
  __syncthreads();
  int lane = tid & 63, wid = tid >> 6;
  int qy = wid >> 1, qx = wid & 1;
  int ty = qy * 8 + (lane >> 3), tx = qx * 8 + (lane & 7);
  float acc[4] = {0.f, 0.f, 0.f, 0.f};
#pragma unroll 1
  for (int ic = 0; ic < 16; ++ic) {
    const float* t = st + ic * 360 + ty * 20 + tx;
    float i3[3][3];
#pragma unroll
    for (int dy = 0; dy < 3; ++dy)
#pragma unroll
      for (int dx = 0; dx < 3; ++dx) i3[dy][dx] = t[dy * 20 + dx];
    const float* wp = fwd2 + ic * 16;  // scalar loads
#pragma unroll
    for (int p = 0; p < 4; ++p) {
      int a = p >> 1, b2 = p & 1;
#pragma unroll
      for (int tp = 0; tp < 4; ++tp) {
        int dy = tp >> 1, dx = tp & 1;
        acc[p] = fmaf(i3[a + dy][b2 + dx], wp[p * 4 + tp], acc[p]);
      }
    }
  }
  float bv = bias[0];
  int Y = 2 * (R0 + ty), X = 2 * (C0 + tx);
  float* op = out + (size_t)b * 65536 + Y * 256 + X;
  float2 r0v, r1v;
  r0v.x = fminf(1.0f, fmaxf(-1.0f, acc[0] + bv));
  r0v.y = fminf(1.0f, fmaxf(-1.0f, acc[1] + bv));
  r1v.x = fminf(1.0f, fmaxf(-1.0f, acc[2] + bv));
  r1v.y = fminf(1.0f, fmaxf(-1.0f, acc[3] + bv));
  *(float2*)op = r0v;
  *(float2*)(op + 256) = r1v;
}

extern "C" void kernel_launch(void* const* d_in, const int* in_sizes, int n_in,
                              void* d_out, int out_size, void* d_ws, size_t ws_size,
                              hipStream_t stream) {
  const float* x   = (const float*)d_in[0];
  const float* e1w = (const float*)d_in[1];
  const float* e1b = (const float*)d_in[2];
  const float* e2w = (const float*)d_in[3];
  const float* e2b = (const float*)d_in[4];
  const float* cb  = (const float*)d_in[5];
  const float* d1w = (const float*)d_in[6];
  const float* d1b = (const float*)d_in[7];
  const float* d2w = (const float*)d_in[8];
  const float* d2b = (const float*)d_in[9];

  float* out = (float*)d_out;
  float* y       = out;                       // [32,1,256,256] = 2097152
  float* idxout  = out + 2097152;             // [32,64,64]     = 131072 (as float)
  float* lossout = out + 2097152 + 131072;    // scalar

  float* ws = (float*)d_ws;
  float* h1      = ws;                        // [32,16,128,128] = 8388608 floats
  float* h2      = ws + 8388608;              // [32,32,64,64]   = 4194304 floats
  float* fwe2    = ws + 12583424;             // 4608
  float* fwd1    = ws + 12588032;             // 8192
  float* fwd2    = ws + 12596224;             // 256
  // partial[2048] reuses the h1 region (dead between enc2 and dec1; k_loss
  // consumes it before k_dec1 writes d1o there — same-stream ordering).
  float* partial = ws;                        // 2048 floats
  float* d1o     = h1;                        // dec1 output reuses h1 (after loss)

  k_fold<<<dim3(51), 256, 0, stream>>>(e2w, d1w, d2w, fwe2, fwd1, fwd2);
  k_enc1<<<dim3(2048), 256, 0, stream>>>(x, e1w, e1b, h1);
  k_enc2<<<dim3(64, 32), 256, 0, stream>>>(h1, fwe2, e2b, h2);
  k_vq<<<dim3(2048), 256, 0, stream>>>(h2, cb, idxout, partial);
  k_loss<<<dim3(1), 256, 0, stream>>>(partial, lossout);
  k_dec1<<<dim3(32, 32), 256, 0, stream>>>(h2, fwd1, d1b, d1o);
  k_dec2<<<dim3(64, 32), 256, 0, stream>>>(d1o, fwd2, d2b, y);
}